// Round 9
// baseline (485.220 us; speedup 1.0000x reference)
//
#include <hip/hip_runtime.h>
#include <math.h>

// GatedCrossAttentionFusion on MI355X (gfx950), bf16 MFMA pipeline.
// B=16384, VD=2048, SD=1024, CD=512, H=256, HEADS=4, DH=64.
//
// Pipeline (all bf16 intermediates in ws):
//  K0 cvt_all   : fp32->bf16 conversion of ALL fp32 operands in one
//                 grid-strided stream: weights (Wv,Ws,Wc,in_w,out_w,g1w -> w0)
//                 and activations fv,fs -> Abf (the dead-until-K2/K3 qkv|ctx
//                 region; |Av|+|As| = 50331648 u16 = |qkv|+|ctx| exactly).
//  K1 gemm_ln   : {Av,As,fc} @ W.T + bias -> LayerNorm -> stack (B*3,256) bf16
//  K2 gemm_qkv  : stack @ in_w.T + in_b -> qkv (overwrites Av)
//  K3 attn_k    : per-b attention -> ctx (overwrites As tail)
//  K4 outproj_k : ctx @ out_w.T + out_b + stack -> LN -> gating MLP -> outputs
//
// Ledger: R8 proved A-as-bf16-gld16 staging cuts K1 130->87us, but cvt_a (2
// loads/thread, 24576 tiny blocks) ran at 2.3 TB/s (issue-starved, NOT BW:
// 201MB should be ~35us). R9: grid-strided cvt_all (13 indep iters/thread for
// MLP) + counted-vmcnt 3-buffer schedule for K1 slots 0/1 (R3's pattern, now
// unmasked since the A-VGPR path is gone).

typedef unsigned short u16;
typedef __bf16 bf16x8 __attribute__((ext_vector_type(8)));
typedef float fx4 __attribute__((ext_vector_type(4)));

#define MFMA_BF16(A_, B_, C_) __builtin_amdgcn_mfma_f32_16x16x32_bf16((A_), (B_), (C_), 0, 0, 0)
#define WAIT_VM(N) asm volatile("s_waitcnt vmcnt(" #N ")" ::: "memory")

__device__ __forceinline__ float bf2f(u16 s) {
    union { float f; unsigned u; } c; c.u = ((unsigned)s) << 16; return c.f;
}
__device__ __forceinline__ u16 f2bf(float f) {
    union { float f; unsigned u; } c; c.f = f;
    return (u16)((c.u + 0x7fffu + ((c.u >> 16) & 1u)) >> 16);
}
// a,b are packed bf16 pairs (little-endian: low u16 = even element)
__device__ __forceinline__ float bfpair_dot(unsigned a, unsigned b) {
    union { unsigned u; float f; } al, ah, bl, bh;
    al.u = a << 16; ah.u = a & 0xffff0000u;
    bl.u = b << 16; bh.u = b & 0xffff0000u;
    return al.f * bl.f + ah.f * bh.f;
}
__device__ __forceinline__ void gld16(void* l, const void* g) {
    __builtin_amdgcn_global_load_lds((const __attribute__((address_space(1))) void*)g,
                                     (__attribute__((address_space(3))) void*)l, 16, 0, 0);
}

// ------------------------------------------- K0: all fp32->bf16 conversions
// Grid-strided: 2048 blocks x 256 threads x 13 iters covers 6445056 chunks of
// 8 elems (weights 153600 chunks -> wdst, then fv|fs 6291456 chunks -> adst).
// All region boundaries are multiples of 8. Independent iterations give each
// thread 13 in-flight load pairs (cvt_a at 2 loads/thread ran issue-starved
// at 2.3 TB/s).
__global__ __launch_bounds__(256) void cvt_all(
    const float* Wv, const float* Ws, const float* Wc,
    const float* inw, const float* outw, const float* g1w,
    const float* fv, const float* fs, u16* wdst, u16* adst) {
    size_t tid = (size_t)blockIdx.x * 256 + threadIdx.x;
    #pragma unroll 2
    for (int it = 0; it < 13; ++it) {
        size_t c = tid + (size_t)it * (2048 * 256);
        if (c >= 6445056) continue;
        size_t idx8 = c * 8;
        const float* src; size_t rel; u16* dst;
        if (idx8 < 1228800) {
            dst = wdst + idx8;
            if      (idx8 <  524288) { src = Wv;   rel = idx8; }
            else if (idx8 <  786432) { src = Ws;   rel = idx8 -  524288; }
            else if (idx8 <  917504) { src = Wc;   rel = idx8 -  786432; }
            else if (idx8 < 1114112) { src = inw;  rel = idx8 -  917504; }
            else if (idx8 < 1179648) { src = outw; rel = idx8 - 1114112; }
            else                     { src = g1w;  rel = idx8 - 1179648; }
        } else {
            size_t a = idx8 - 1228800;
            dst = adst + a;
            if (a < 33554432) { src = fv; rel = a; }
            else              { src = fs; rel = a - 33554432; }
        }
        float4 x = *(const float4*)(src + rel);
        float4 y = *(const float4*)(src + rel + 4);
        union { u16 us[8]; uint4 v; } pk;
        pk.us[0] = f2bf(x.x); pk.us[1] = f2bf(x.y); pk.us[2] = f2bf(x.z); pk.us[3] = f2bf(x.w);
        pk.us[4] = f2bf(y.x); pk.us[5] = f2bf(y.y); pk.us[6] = f2bf(y.z); pk.us[7] = f2bf(y.w);
        *(uint4*)dst = pk.v;
    }
}

// ------------------------------------------------- K1: input GEMM + LayerNorm
// BM=64, BN=256(=H), BK=32, 4 waves. 1D grid of 768 blocks, longest-job-first.
// Slots 0/1 (bf16 A): 3-buffer depth-2 counted-vmcnt pipeline (5 gld16/thread
// per tile -> WAIT_VM(5), raw s_barrier, loads never drain to 0 mid-loop).
// Slot 2 (fc fp32): R8's dbuf + syncthreads path (fp32->VGPR->cvt->ds_write).
__global__ __launch_bounds__(256, 2) void gemm_ln(
    const float* fcIn, const u16* Av, const u16* As,
    const u16* wWv, const u16* wWs, const u16* wWc,
    const float* bv, const float* gv, const float* bev,
    const float* bs, const float* gs, const float* bes,
    const float* bc, const float* gc_, const float* bec,
    u16* stack) {
    // slot<2: buf k @ k*20480 (A 4096B = 256x16B chunks, B 16384B = 1024 chunks)
    // slot=2: A dbuf @0/5120 ([64][40] bf16), B dbuf @10240/26624 (16KB each)
    // epilogue: sC overlay @0 (32KB), red arrays @61440.
    __shared__ alignas(16) char smem[64000];
    u16* sC = (u16*)smem;
    float* redS = (float*)(smem + 61440);   // [64][4]
    float* redQ = (float*)(smem + 62464);   // [64][4]
    float* mvS  = (float*)(smem + 63488);   // [64][2] mean,rstd

    int bid = blockIdx.x;
    int slot, mblk;
    if (bid < 256)      { slot = 0; mblk = bid; }
    else if (bid < 512) { slot = 1; mblk = bid - 256; }
    else                { slot = 2; mblk = bid - 512; }

    const u16* Ab; const float* Af; const u16* W;
    const float* bias; const float* gg; const float* be; int K;
    if (slot == 0)      { Ab = Av; Af = 0;    W = wWv; bias = bv; gg = gv;  be = bev; K = 2048; }
    else if (slot == 1) { Ab = As; Af = 0;    W = wWs; bias = bs; gg = gs;  be = bes; K = 1024; }
    else                { Ab = 0;  Af = fcIn; W = wWc; bias = bc; gg = gc_; be = bec; K = 512;  }

    int t = threadIdx.x, wv = t >> 6, ln = t & 63, q = ln >> 4, l15 = ln & 15;
    int m0 = mblk * 64;

    fx4 zero = {0.f, 0.f, 0.f, 0.f};
    fx4 acc[4][4];
    #pragma unroll
    for (int mi = 0; mi < 4; ++mi)
        #pragma unroll
        for (int ni = 0; ni < 4; ++ni) acc[mi][ni] = zero;

    // B map: 1024 chunks, pos p of row n holds k-chunk p^((n>>1)&3)
    int bN[4], bKc[4], bDst[4];
    #pragma unroll
    for (int i = 0; i < 4; ++i) {
        int d = wv * 256 + i * 64 + ln;
        bN[i] = d >> 2;
        bKc[i] = (d & 3) ^ ((bN[i] >> 1) & 3);
        bDst[i] = (wv * 256 + i * 64) * 16;
    }
    int niter = K >> 5;

    if (slot < 2) {
        // A map: 256 chunks, chunk t: row r=t>>2, pos p=t&3 holds k-chunk
        // p^((r>>1)&3)
        int aR = t >> 2, aP = t & 3;
        int aKc = aP ^ ((aR >> 1) & 3);
        int aSw = (l15 >> 1) & 3;

#define LN_ISS(ktile, bufoff)                                                     \
        {                                                                         \
            char* bA_ = smem + (bufoff);                                          \
            char* bB_ = bA_ + 4096;                                               \
            gld16(bA_ + t * 16, Ab + (size_t)(m0 + aR) * K + (ktile) * 32 + aKc * 8); \
            _Pragma("unroll")                                                     \
            for (int i_ = 0; i_ < 4; ++i_)                                        \
                gld16(bB_ + bDst[i_], W + (size_t)bN[i_] * K + (ktile) * 32 + bKc[i_] * 8); \
        }

        LN_ISS(0, 0);
        LN_ISS(1, 20480);
        int cb = 0;
        for (int kt = 0; kt < niter; ++kt) {
            if (kt + 1 < niter) { WAIT_VM(5); } else { WAIT_VM(0); }
            __builtin_amdgcn_sched_barrier(0);
            __builtin_amdgcn_s_barrier();
            __builtin_amdgcn_sched_barrier(0);
            int nb = cb + 2; if (nb >= 3) nb -= 3;
            if (kt + 2 < niter) LN_ISS(kt + 2, nb * 20480);

            const u16* sAc = (const u16*)(smem + cb * 20480);
            const u16* sBc = (const u16*)(smem + cb * 20480 + 4096);
            bf16x8 af[4], bfr[4];
            #pragma unroll
            for (int mi = 0; mi < 4; ++mi) {
                int r = mi * 16 + l15;
                af[mi] = *(const bf16x8*)(sAc + (r * 4 + (q ^ aSw)) * 8);
            }
            #pragma unroll
            for (int ni = 0; ni < 4; ++ni) {
                int n = wv * 64 + ni * 16 + l15;
                int ch = n * 4 + (q ^ ((n >> 1) & 3));
                bfr[ni] = *(const bf16x8*)(sBc + ch * 8);
            }
            __builtin_amdgcn_s_setprio(1);
            #pragma unroll
            for (int mi = 0; mi < 4; ++mi)
                #pragma unroll
                for (int ni = 0; ni < 4; ++ni)
                    acc[mi][ni] = MFMA_BF16(af[mi], bfr[ni], acc[mi][ni]);
            __builtin_amdgcn_s_setprio(0);
            cb += 1; if (cb >= 3) cb -= 3;
        }
#undef LN_ISS
    } else {
        // fc fp32 path (R8): A via global->VGPR->cvt->ds_write, dbuf+syncthreads
        int aR = t >> 2, aP = t & 3;
        const float* aBase = Af + (size_t)(m0 + aR) * 512 + aP * 8;
        int sAwOff = aR * 40 + aP * 8;
        {
            float4 f0 = *(const float4*)(aBase);
            float4 f1 = *(const float4*)(aBase + 4);
            #pragma unroll
            for (int i = 0; i < 4; ++i)
                gld16(smem + 10240 + bDst[i], W + (size_t)bN[i] * 512 + bKc[i] * 8);
            union { u16 us[8]; uint4 v; } pk;
            pk.us[0] = f2bf(f0.x); pk.us[1] = f2bf(f0.y); pk.us[2] = f2bf(f0.z); pk.us[3] = f2bf(f0.w);
            pk.us[4] = f2bf(f1.x); pk.us[5] = f2bf(f1.y); pk.us[6] = f2bf(f1.z); pk.us[7] = f2bf(f1.w);
            *(uint4*)((u16*)smem + sAwOff) = pk.v;
        }
        __syncthreads();
        for (int kt = 0; kt < niter; ++kt) {
            int cur = kt & 1, nxt_b = (kt + 1) & 1;
            u16* sAc = (u16*)(smem + cur * 5120);
            u16* sBc = (u16*)(smem + 10240 + cur * 16384);
            int has_next = (kt + 1) < niter;

            float4 nf0, nf1;
            if (has_next) {
                nf0 = *(const float4*)(aBase + (kt + 1) * 32);
                nf1 = *(const float4*)(aBase + (kt + 1) * 32 + 4);
                char* sBn = smem + 10240 + nxt_b * 16384;
                #pragma unroll
                for (int i = 0; i < 4; ++i)
                    gld16(sBn + bDst[i], W + (size_t)bN[i] * 512 + (kt + 1) * 32 + bKc[i] * 8);
            }
            bf16x8 af[4], bfr[4];
            #pragma unroll
            for (int mi = 0; mi < 4; ++mi)
                af[mi] = *(const bf16x8*)(sAc + (mi * 16 + l15) * 40 + q * 8);
            #pragma unroll
            for (int ni = 0; ni < 4; ++ni) {
                int n = wv * 64 + ni * 16 + l15;
                int ch = n * 4 + (q ^ ((n >> 1) & 3));
                bfr[ni] = *(const bf16x8*)(sBc + ch * 8);
            }
            #pragma unroll
            for (int mi = 0; mi < 4; ++mi)
                #pragma unroll
                for (int ni = 0; ni < 4; ++ni)
                    acc[mi][ni] = MFMA_BF16(af[mi], bfr[ni], acc[mi][ni]);
            if (has_next) {
                union { u16 us[8]; uint4 v; } pk;
                pk.us[0] = f2bf(nf0.x); pk.us[1] = f2bf(nf0.y); pk.us[2] = f2bf(nf0.z); pk.us[3] = f2bf(nf0.w);
                pk.us[4] = f2bf(nf1.x); pk.us[5] = f2bf(nf1.y); pk.us[6] = f2bf(nf1.z); pk.us[7] = f2bf(nf1.w);
                *(uint4*)((u16*)(smem + nxt_b * 5120) + sAwOff) = pk.v;
            }
            __syncthreads();
        }
    }

    // epilogue: bias, LN stats from registers, normalize, write bf16
    float biasv[4], gvv[4], bevv[4];
    #pragma unroll
    for (int ni = 0; ni < 4; ++ni) {
        int col = wv * 64 + ni * 16 + l15;
        biasv[ni] = bias[col]; gvv[ni] = gg[col]; bevv[ni] = be[col];
    }
    #pragma unroll
    for (int mi = 0; mi < 4; ++mi)
        #pragma unroll
        for (int ni = 0; ni < 4; ++ni)
            #pragma unroll
            for (int r = 0; r < 4; ++r) acc[mi][ni][r] += biasv[ni];
    #pragma unroll
    for (int mi = 0; mi < 4; ++mi) {
        #pragma unroll
        for (int r = 0; r < 4; ++r) {
            float s = 0.f, qq = 0.f;
            #pragma unroll
            for (int ni = 0; ni < 4; ++ni) { float x = acc[mi][ni][r]; s += x; qq += x * x; }
            #pragma unroll
            for (int m = 1; m < 16; m <<= 1) { s += __shfl_xor(s, m, 64); qq += __shfl_xor(qq, m, 64); }
            if (l15 == 0) { int rho = mi * 16 + q * 4 + r; redS[rho * 4 + wv] = s; redQ[rho * 4 + wv] = qq; }
        }
    }
    __syncthreads();
    if (t < 64) {
        float s = redS[t * 4] + redS[t * 4 + 1] + redS[t * 4 + 2] + redS[t * 4 + 3];
        float qq = redQ[t * 4] + redQ[t * 4 + 1] + redQ[t * 4 + 2] + redQ[t * 4 + 3];
        float mean = s * (1.f / 256.f);
        float var = qq * (1.f / 256.f) - mean * mean;
        mvS[t * 2] = mean; mvS[t * 2 + 1] = rsqrtf(var + 1e-5f);
    }
    __syncthreads();
    #pragma unroll
    for (int mi = 0; mi < 4; ++mi) {
        #pragma unroll
        for (int r = 0; r < 4; ++r) {
            int rho = mi * 16 + q * 4 + r;
            float mean = mvS[rho * 2], rstd = mvS[rho * 2 + 1];
            #pragma unroll
            for (int ni = 0; ni < 4; ++ni) {
                int col = wv * 64 + ni * 16 + l15;
                float x = (acc[mi][ni][r] - mean) * rstd * gvv[ni] + bevv[ni];
                sC[rho * 256 + col] = f2bf(x);
            }
        }
    }
    __syncthreads();
    u16* outp = stack + (size_t)m0 * 768 + slot * 256;
    #pragma unroll
    for (int it = 0; it < 8; ++it) {
        int idx = t + it * 256;
        int row = idx >> 5, c = idx & 31;
        uint4 v = *(const uint4*)(sC + row * 256 + c * 8);
        *(uint4*)(outp + (size_t)row * 768 + c * 8) = v;
    }
}

// ------------------------------------------------------ K2: qkv = stack@in_w.T
// R3 variant verbatim. M=49152, K=256, N=768. BM=128, BN=128, 4 waves in 2x2.
// 3-buffer depth-2 counted-vmcnt pipeline.
__global__ __launch_bounds__(256, 3) void gemm_qkv(const u16* stack, const u16* W, const float* in_b,
                                                   u16* qkv) {
    __shared__ alignas(16) char smem[49152];
    u16* sC = (u16*)smem;            // epilogue [128][128] overlay

    int t = threadIdx.x, wv = t >> 6, ln = t & 63, q = ln >> 4, l15 = ln & 15;
    int n0 = blockIdx.x * 128, m0 = blockIdx.y * 128;
    int wr = wv >> 1, wc = wv & 1;

    fx4 zero = {0.f, 0.f, 0.f, 0.f};
    fx4 acc[4][4];
    #pragma unroll
    for (int mi = 0; mi < 4; ++mi)
        #pragma unroll
        for (int ni = 0; ni < 4; ++ni) acc[mi][ni] = zero;

    int sR[2], sKc[2];
    #pragma unroll
    for (int i = 0; i < 2; ++i) {
        int d = wv * 128 + i * 64 + ln;
        sR[i] = d >> 2;
        sKc[i] = (d & 3) ^ ((sR[i] >> 1) & 3);
    }

#define QK_ISSUE(ktile, bufoff)                                                         \
    {                                                                                   \
        char* bA_ = smem + (bufoff);                                                    \
        char* bB_ = bA_ + 8192;                                                         \
        _Pragma("unroll")                                                               \
        for (int i_ = 0; i_ < 2; ++i_) {                                                \
            gld16(bA_ + (wv * 128 + i_ * 64) * 16,                                      \
                  stack + (size_t)(m0 + sR[i_]) * 256 + (ktile) * 32 + sKc[i_] * 8);    \
            gld16(bB_ + (wv * 128 + i_ * 64) * 16,                                      \
                  W + (size_t)(n0 + sR[i_]) * 256 + (ktile) * 32 + sKc[i_] * 8);        \
        }                                                                               \
    }

    QK_ISSUE(0, 0);
    QK_ISSUE(1, 16384);
    int cb = 0;
    for (int kt = 0; kt < 8; ++kt) {
        if (kt < 7) { WAIT_VM(4); } else { WAIT_VM(0); }
        __builtin_amdgcn_sched_barrier(0);
        __builtin_amdgcn_s_barrier();
        __builtin_amdgcn_sched_barrier(0);
        int nb = cb + 2; if (nb >= 3) nb -= 3;
        if (kt + 2 < 8) QK_ISSUE(kt + 2, nb * 16384);

        const u16* sAc = (const u16*)(smem + cb * 16384);
        const u16* sBc = (const u16*)(smem + cb * 16384 + 8192);
        bf16x8 af[4], bfr[4];
        #pragma unroll
        for (int mi = 0; mi < 4; ++mi) {
            int r = wr * 64 + mi * 16 + l15;
            int ch = r * 4 + (q ^ ((r >> 1) & 3));
            af[mi] = *(const bf16x8*)(sAc + ch * 8);
        }
        #pragma unroll
        for (int ni = 0; ni < 4; ++ni) {
            int n = wc * 64 + ni * 16 + l15;
            int ch = n * 4 + (q ^ ((n >> 1) & 3));
            bfr[ni] = *(const bf16x8*)(sBc + ch * 8);
        }
        __builtin_amdgcn_s_setprio(1);
        #pragma unroll
        for (int mi = 0; mi < 4; ++mi)
            #pragma unroll
            for (int ni = 0; ni < 4; ++ni)
                acc[mi][ni] = MFMA_BF16(af[mi], bfr[ni], acc[mi][ni]);
        __builtin_amdgcn_s_setprio(0);
        cb += 1; if (cb >= 3) cb -= 3;
    }
#undef QK_ISSUE
    __syncthreads();   // all waves done reading bufs before sC overlay

    float biasv[4];
    #pragma unroll
    for (int ni = 0; ni < 4; ++ni) biasv[ni] = in_b[n0 + wc * 64 + ni * 16 + l15];
    #pragma unroll
    for (int mi = 0; mi < 4; ++mi)
        #pragma unroll
        for (int ni = 0; ni < 4; ++ni)
            #pragma unroll
            for (int r = 0; r < 4; ++r) {
                int rl = wr * 64 + mi * 16 + q * 4 + r;
                int cl = wc * 64 + ni * 16 + l15;
                sC[rl * 128 + cl] = f2bf(acc[mi][ni][r] + biasv[ni]);
            }
    __syncthreads();
    #pragma unroll
    for (int it = 0; it < 8; ++it) {
        int idx = t + it * 256;
        int row = idx >> 4, c = idx & 15;
        uint4 v = *(const uint4*)(sC + row * 128 + c * 8);
        *(uint4*)(qkv + (size_t)(m0 + row) * 768 + n0 + c * 8) = v;
    }
}

// ------------------------------------------------------------- K3: attention
// 8 b's per block. qkv row per (b,i): [q(256)|k(256)|v(256)].
__global__ __launch_bounds__(256) void attn_k(const u16* qkv, u16* ctx) {
    __shared__ alignas(16) char smem[38016];
    u16* qs = (u16*)smem;                 // 8*2304 bf16
    float* sS = (float*)(smem + 36864);   // 288 scores/probs: [b][h][i][j]

    int t = threadIdx.x, wv = t >> 6, ln = t & 63;
    size_t base = (size_t)blockIdx.x * 8 * 2304;
    #pragma unroll
    for (int i = 0; i < 9; ++i) {
        int d = wv * 576 + i * 64;
        gld16((char*)smem + (size_t)d * 16, qkv + base + (size_t)(d + ln) * 8);
    }
    __syncthreads();
    // scores: 288 items = 8b*4h*9(i,j)
    #pragma unroll
    for (int it = 0; it < 2; ++it) {
        int idx = t + it * 256;
        if (idx < 288) {
            int b = idx / 36, rem = idx % 36, h = rem / 9, pp = rem % 9, i = pp / 3, j = pp % 3;
            const u16* qp = qs + b * 2304 + i * 768 + h * 64;
            const u16* kp = qs + b * 2304 + j * 768 + 256 + h * 64;
            float acc = 0.f;
            #pragma unroll
            for (int c = 0; c < 8; ++c) {
                uint4 qa = *(const uint4*)(qp + c * 8);
                uint4 ka = *(const uint4*)(kp + c * 8);
                acc += bfpair_dot(qa.x, ka.x) + bfpair_dot(qa.y, ka.y) +
                       bfpair_dot(qa.z, ka.z) + bfpair_dot(qa.w, ka.w);
            }
            sS[idx] = acc * 0.125f;  // /sqrt(64)
        }
    }
    __syncthreads();
    if (t < 96) {  // softmax over j, t = b*12 + h*3 + i
        int b3 = t * 3;
        float s0 = sS[b3], s1 = sS[b3 + 1], s2 = sS[b3 + 2];
        float m = fmaxf(s0, fmaxf(s1, s2));
        float e0 = __expf(s0 - m), e1 = __expf(s1 - m), e2 = __expf(s2 - m);
        float inv = 1.f / (e0 + e1 + e2);
        sS[b3] = e0 * inv; sS[b3 + 1] = e1 * inv; sS[b3 + 2] = e2 * inv;
    }
    __syncthreads();
    // ctx: 768 items = 8b * 3i * 32 chunks-of-8
    #pragma unroll
    for (int it = 0; it < 3; ++it) {
        int idx = t + it * 256;
        int b = idx / 96, rem = idx % 96, i = rem / 32, c = rem & 31, h = c >> 3;
        int pbase = b * 36 + h * 9 + i * 3;
        float o[8];
        #pragma unroll
        for (int e = 0; e < 8; ++e) o[e] = 0.f;
        #pragma unroll
        for (int j = 0; j < 3; ++j) {
            float p = sS[pbase + j];
            uint4 va = *(const uint4*)(qs + b * 2304 + j * 768 + 512 + c * 8);
            unsigned uu[4] = {va.x, va.y, va.z, va.w};
            #pragma unroll
            for (int pr = 0; pr < 4; ++pr) {
                union { unsigned u; float f; } lo, hi;
                lo.u = uu[pr] << 16; hi.u = uu[pr] & 0xffff0000u;
                o[2 * pr]     += p * lo.f;
                o[2 * pr + 1] += p * hi.f;
            }
        }
        union { u16 us[8]; uint4 v; } pk;
        #pragma unroll
        for (int e = 0; e < 8; ++e) pk.us[e] = f2bf(o[e]);
        *(uint4*)(ctx + (size_t)(blockIdx.x * 8 + b) * 768 + i * 256 + c * 8) = pk.v;
    }
}

// -------------------- K4: out-proj + residual + LN + gating MLP + fused output
// R3 variant verbatim. BM=48 (16 b's), BN=256, K=256.
__global__ __launch_bounds__(256) void outproj_k(
    const u16* ctx, const u16* W, const float* out_b, const u16* stack,
    const float* gn, const float* gb, const u16* g1w, const float* g1b,
    const float* g2w, const float* g2b, float* outF, float* outG) {
    __shared__ alignas(16) char smem[40960];
    u16* r1 = (u16*)smem;                         // 24576B
    u16* sB = (u16*)(smem + 24576);               // 16384B (k-loop)
    float* redS = (float*)(smem + 24576);         // 48*4
    float* redQ = redS + 192;
    float* mvS = redQ + 192;                      // 48*2
    float* h1S = (float*)(smem + 26624);          // [16][64]
    float* lgS = (float*)(smem + 30720);          // 48 logits
    float* gateS = lgS + 48;                      // 48 gates

    int t = threadIdx.x, wv = t >> 6, ln = t & 63, q = ln >> 4, l15 = ln & 15;
    int gr0 = blockIdx.x * 48, b0 = blockIdx.x * 16;

    // stage full ctx tile [48][256] once, chunk pos p holds k-chunk p^(row&7)
    #pragma unroll
    for (int i = 0; i < 6; ++i) {
        int d = wv * 384 + i * 64 + ln;
        int row = d >> 5, p = d & 31;
        int kc = p ^ (row & 7);
        gld16((char*)r1 + (wv * 384 + i * 64) * 16, ctx + (size_t)(gr0 + row) * 256 + kc * 8);
    }
    __syncthreads();

    fx4 zero = {0.f, 0.f, 0.f, 0.f};
    fx4 acc[3][4];
    #pragma unroll
    for (int mi = 0; mi < 3; ++mi)
        #pragma unroll
        for (int ni = 0; ni < 4; ++ni) acc[mi][ni] = zero;

    for (int kt = 0; kt < 8; ++kt) {
        #pragma unroll
        for (int i = 0; i < 4; ++i) {
            int d = wv * 256 + i * 64 + ln;
            int n = d >> 2, p = d & 3;
            int kc = p ^ ((n >> 1) & 3);
            gld16((char*)sB + (wv * 256 + i * 64) * 16, W + (size_t)n * 256 + kt * 32 + kc * 8);
        }
        __syncthreads();
        bf16x8 af[3], bfr[4];
        #pragma unroll
        for (int mi = 0; mi < 3; ++mi) {
            int row = mi * 16 + l15;
            int ch = row * 32 + ((kt * 4 + q) ^ (row & 7));
            af[mi] = *(const bf16x8*)(r1 + ch * 8);
        }
        #pragma unroll
        for (int ni = 0; ni < 4; ++ni) {
            int n = wv * 64 + ni * 16 + l15;
            int ch = n * 4 + (q ^ ((n >> 1) & 3));
            bfr[ni] = *(const bf16x8*)(sB + ch * 8);
        }
        #pragma unroll
        for (int mi = 0; mi < 3; ++mi)
            #pragma unroll
            for (int ni = 0; ni < 4; ++ni)
                acc[mi][ni] = MFMA_BF16(af[mi], bfr[ni], acc[mi][ni]);
        __syncthreads();
    }

    // stage stack tile [48][256] (contiguous in global) into r1
    #pragma unroll
    for (int i = 0; i < 6; ++i) {
        int d = wv * 384 + i * 64 + ln;
        gld16((char*)r1 + (wv * 384 + i * 64) * 16, stack + (size_t)gr0 * 256 + (size_t)d * 8);
    }
    __syncthreads();

    float obv[4], gnv[4], gbv[4];
    #pragma unroll
    for (int ni = 0; ni < 4; ++ni) {
        int col = wv * 64 + ni * 16 + l15;
        obv[ni] = out_b[col]; gnv[ni] = gn[col]; gbv[ni] = gb[col];
    }
    #pragma unroll
    for (int mi = 0; mi < 3; ++mi)
        #pragma unroll
        for (int ni = 0; ni < 4; ++ni)
            #pragma unroll
            for (int r = 0; r < 4; ++r) {
                int rho = mi * 16 + q * 4 + r;
                int col = wv * 64 + ni * 16 + l15;
                acc[mi][ni][r] += obv[ni] + bf2f(r1[rho * 256 + col]);
            }
    // LN stats
    #pragma unroll
    for (int mi = 0; mi < 3; ++mi) {
        #pragma unroll
        for (int r = 0; r < 4; ++r) {
            float s = 0.f, qq = 0.f;
            #pragma unroll
            for (int ni = 0; ni < 4; ++ni) { float x = acc[mi][ni][r]; s += x; qq += x * x; }
            #pragma unroll
            for (int m = 1; m < 16; m <<= 1) { s += __shfl_xor(s, m, 64); qq += __shfl_xor(qq, m, 64); }
            if (l15 == 0) { int rho = mi * 16 + q * 4 + r; redS[rho * 4 + wv] = s; redQ[rho * 4 + wv] = qq; }
        }
    }
    __syncthreads();
    if (t < 48) {
        float s = redS[t * 4] + redS[t * 4 + 1] + redS[t * 4 + 2] + redS[t * 4 + 3];
        float qq = redQ[t * 4] + redQ[t * 4 + 1] + redQ[t * 4 + 2] + redQ[t * 4 + 3];
        float mean = s * (1.f / 256.f);
        float var = qq * (1.f / 256.f) - mean * mean;
        mvS[t * 2] = mean; mvS[t * 2 + 1] = rsqrtf(var + 1e-5f);
    }
    __syncthreads();
    // normalize -> rowBuf (r1, swizzled as [16 b][96 chunks], chunk = bl*96 + (kidx^(bl&7)))
    #pragma unroll
    for (int mi = 0; mi < 3; ++mi) {
        #pragma unroll
        for (int r = 0; r < 4; ++r) {
            int rho = mi * 16 + q * 4 + r;
            float mean = mvS[rho * 2], rstd = mvS[rho * 2 + 1];
            int bl = rho / 3, sl = rho - bl * 3;
            #pragma unroll
            for (int ni = 0; ni < 4; ++ni) {
                int col = wv * 64 + ni * 16 + l15;
                float x = (acc[mi][ni][r] - mean) * rstd * gnv[ni] + gbv[ni];
                int k = sl * 256 + col;
                int kidx = k >> 3, wn = k & 7;
                r1[(bl * 96 + (kidx ^ (bl & 7))) * 8 + wn] = f2bf(x);
            }
        }
    }
    __syncthreads();
    // gating MFMA: h1[16 b][64] = attended_flat(16x768) @ g1w.T ; wave wv owns cols wv*16..+15
    fx4 ag = zero;
    for (int kt = 0; kt < 24; ++kt) {
        int bl = l15;
        int kidx = kt * 4 + q;
        bf16x8 afr = *(const bf16x8*)(r1 + (bl * 96 + (kidx ^ (bl & 7))) * 8);
        int n = wv * 16 + l15;
        bf16x8 bfr2 = *(const bf16x8*)(g1w + (size_t)n * 768 + kt * 32 + q * 8);
        ag = MFMA_BF16(afr, bfr2, ag);
    }
    #pragma unroll
    for (int r = 0; r < 4; ++r) {
        int bl = q * 4 + r, n = wv * 16 + l15;
        float x = ag[r] + g1b[n];
        h1S[bl * 64 + n] = 0.5f * x * (1.f + erff(x * 0.70710678118f));
    }
    __syncthreads();
    if (t < 48) {  // logits: t = bl*3 + s
        int bl = t / 3, s = t - bl * 3;
        float a = g2b[s];
        #pragma unroll
        for (int k = 0; k < 64; ++k) a += h1S[bl * 64 + k] * g2w[s * 64 + k];
        lgS[t] = a;
    }
    __syncthreads();
    if (t < 48) {
        int bl = t / 3, s = t - bl * 3;
        float l0 = lgS[bl * 3], l1 = lgS[bl * 3 + 1], l2 = lgS[bl * 3 + 2];
        float m = fmaxf(l0, fmaxf(l1, l2));
        float e0 = __expf(l0 - m), e1 = __expf(l1 - m), e2 = __expf(l2 - m);
        float inv = 1.f / (e0 + e1 + e2);
        float gsel = ((s == 0) ? e0 : (s == 1) ? e1 : e2) * inv;
        gateS[t] = gsel;
        outG[(size_t)(b0 + bl) * 3 + s] = gsel;
    }
    __syncthreads();
    // fused = sum_s gate[s] * attended[s]
    #pragma unroll
    for (int it = 0; it < 2; ++it) {
        int idx = t + it * 256;
        int b = idx >> 5, c = idx & 31;
        float g0 = gateS[b * 3], g1 = gateS[b * 3 + 1], g2 = gateS[b * 3 + 2];
        float o[8];
        #pragma unroll
        for (int e = 0; e < 8; ++e) o[e] = 0.f;
        #pragma unroll
        for (int s = 0; s < 3; ++s) {
            float gw = (s == 0) ? g0 : (s == 1) ? g1 : g2;
            int kidx = s * 32 + c;
            uint4 raw = *(const uint4*)(r1 + (b * 96 + (kidx ^ (b & 7))) * 8);
            unsigned uu[4] = {raw.x, raw.y, raw.z, raw.w};
            #pragma unroll
            for (int pr = 0; pr < 4; ++pr) {
                union { unsigned u; float f; } lo, hi;
                lo.u = uu[pr] << 16; hi.u = uu[pr] & 0xffff0000u;
                o[2 * pr]     += gw * lo.f;
                o[2 * pr + 1] += gw * hi.f;
            }
        }
        float* op = outF + (size_t)(b0 + b) * 256 + c * 8;
        float4 v0; v0.x = o[0]; v0.y = o[1]; v0.z = o[2]; v0.w = o[3];
        float4 v1; v1.x = o[4]; v1.y = o[5]; v1.z = o[6]; v1.w = o[7];
        *(float4*)op = v0;
        *(float4*)(op + 4) = v1;
    }
}

extern "C" void kernel_launch(void* const* d_in, const int* in_sizes, int n_in,
                              void* d_out, int out_size, void* d_ws, size_t ws_size,
                              hipStream_t stream) {
    (void)in_sizes; (void)n_in; (void)out_size; (void)ws_size;
    const float* fv   = (const float*)d_in[0];
    const float* fs   = (const float*)d_in[1];
    const float* fc   = (const float*)d_in[2];
    const float* Wv   = (const float*)d_in[3];
    const float* bv   = (const float*)d_in[4];
    const float* gv   = (const float*)d_in[5];
    const float* bev  = (const float*)d_in[6];
    const float* Ws   = (const float*)d_in[7];
    const float* bs   = (const float*)d_in[8];
    const float* gs   = (const float*)d_in[9];
    const float* bes  = (const float*)d_in[10];
    const float* Wc   = (const float*)d_in[11];
    const float* bc   = (const float*)d_in[12];
    const float* gc_  = (const float*)d_in[13];
    const float* bec  = (const float*)d_in[14];
    const float* in_w = (const float*)d_in[15];
    const float* in_b = (const float*)d_in[16];
    const float* out_w= (const float*)d_in[17];
    const float* out_b= (const float*)d_in[18];
    const float* gn   = (const float*)d_in[19];
    const float* gb   = (const float*)d_in[20];
    const float* g1w  = (const float*)d_in[21];
    const float* g1b  = (const float*)d_in[22];
    const float* g2w  = (const float*)d_in[23];
    const float* g2b  = (const float*)d_in[24];

    u16* w0    = (u16*)d_ws;
    u16* wWv   = w0;               // 524288
    u16* wWs   = w0 + 524288;      // 262144
    u16* wWc   = w0 + 786432;      // 131072
    u16* wIn   = w0 + 917504;      // 196608
    u16* wOut  = w0 + 1114112;     // 65536
    u16* wG1   = w0 + 1179648;     // 49152
    u16* stack = w0 + 1228800;     // 49152*256
    u16* qkv   = w0 + 13811712;    // 49152*768
    u16* ctx   = w0 + 51560448;    // 49152*256  (total 64143360 u16 = ~128.3 MB)
    // A-bf16 overlay: Av+As = 50331648 u16 == |qkv|+|ctx| exactly. Dead after
    // K1; K2 overwrites qkv (over Av), K3 overwrites ctx (over As tail).
    u16* Abf  = qkv;
    u16* Av   = Abf;               // 33554432 (16384 x 2048)
    u16* Asb  = Abf + 33554432;    // 16777216 (16384 x 1024)
    float* outF = (float*)d_out;
    float* outG = outF + (size_t)16384 * 256;

    cvt_all<<<2048, 256, 0, stream>>>(Wv, Ws, Wc, in_w, out_w, g1w, fv, fs, w0, Abf);
    gemm_ln<<<768, 256, 0, stream>>>(fc, Av, Asb, wWv, wWs, wWc,
                                     bv, gv, bev, bs, gs, bes, bc, gc_, bec, stack);
    gemm_qkv<<<dim3(6, 384), 256, 0, stream>>>(stack, wIn, in_b, qkv);
    attn_k<<<2048, 256, 0, stream>>>(qkv, ctx);
    outproj_k<<<1024, 256, 0, stream>>>(ctx, wOut, out_b, stack, gn, gb,
                                        wG1, g1b, g2w, g2b, outF, outG);
}

// Round 10
// 421.196 us; speedup vs baseline: 1.1520x; 1.1520x over previous
//
#include <hip/hip_runtime.h>
#include <math.h>

// GatedCrossAttentionFusion on MI355X (gfx950), bf16 MFMA pipeline.
// B=16384, VD=2048, SD=1024, CD=512, H=256, HEADS=4, DH=64.
//
// Pipeline (all bf16 intermediates in ws):
//  K0 cvt_w     : fp32->bf16 weight conversion (Wv,Ws,Wc,in_w,out_w,g1w)
//  K1 gemm_ln   : {fv,fs,fc} @ W.T + bias -> LayerNorm -> stack (B*3,256) bf16
//  K2 gemm_qkv  : stack @ in_w.T + in_b -> qkv (B*3,768) bf16
//  K4 outproj_k : FUSED attention (was K3) + ctx @ out_w.T + out_b + stack
//                 -> LN -> gating MLP -> fused+gates
//
// Ledger through R9: K1 local floor ~130us (R2-form dbuf; pre-convert branch
// abandoned: cvt stream costs 88-100us to save 43). R3 config (e2e 430) is
// the best measured baseline; its unaccounted ~295us is K2+K3+K4+gaps.
// R10: K3 fused into K4 -- K4's 48-row tile = 16 b's, attention is block-
// local. Saves the K3 launch + the 50MB ctx round-trip; ctx is computed in
// LDS and written directly into the swizzled r1 layout the GEMM loop reads.

typedef unsigned short u16;
typedef __bf16 bf16x8 __attribute__((ext_vector_type(8)));
typedef float fx4 __attribute__((ext_vector_type(4)));

#define MFMA_BF16(A_, B_, C_) __builtin_amdgcn_mfma_f32_16x16x32_bf16((A_), (B_), (C_), 0, 0, 0)
#define WAIT_VM(N) asm volatile("s_waitcnt vmcnt(" #N ")" ::: "memory")

__device__ __forceinline__ float bf2f(u16 s) {
    union { float f; unsigned u; } c; c.u = ((unsigned)s) << 16; return c.f;
}
__device__ __forceinline__ u16 f2bf(float f) {
    union { float f; unsigned u; } c; c.f = f;
    return (u16)((c.u + 0x7fffu + ((c.u >> 16) & 1u)) >> 16);
}
// a,b are packed bf16 pairs (little-endian: low u16 = even element)
__device__ __forceinline__ float bfpair_dot(unsigned a, unsigned b) {
    union { unsigned u; float f; } al, ah, bl, bh;
    al.u = a << 16; ah.u = a & 0xffff0000u;
    bl.u = b << 16; bh.u = b & 0xffff0000u;
    return al.f * bl.f + ah.f * bh.f;
}
__device__ __forceinline__ void gld16(void* l, const void* g) {
    __builtin_amdgcn_global_load_lds((const __attribute__((address_space(1))) void*)g,
                                     (__attribute__((address_space(3))) void*)l, 16, 0, 0);
}

// ---------------------------------------------------------------- K0: weights
__global__ __launch_bounds__(256) void cvt_w(const float* Wv, const float* Ws, const float* Wc,
                                             const float* inw, const float* outw, const float* g1w,
                                             u16* dst) {
    int idx = blockIdx.x * 256 + threadIdx.x;  // grid covers exactly 1228800
    const float* src; int rel;
    if      (idx <  524288) { src = Wv;   rel = idx; }
    else if (idx <  786432) { src = Ws;   rel = idx -  524288; }
    else if (idx <  917504) { src = Wc;   rel = idx -  786432; }
    else if (idx < 1114112) { src = inw;  rel = idx -  917504; }
    else if (idx < 1179648) { src = outw; rel = idx - 1114112; }
    else                    { src = g1w;  rel = idx - 1179648; }
    dst[idx] = f2bf(src[rel]);
}

// ------------------------------------------------- K1: input GEMM + LayerNorm
// R2-form verbatim (best measured: 127-131us across R2/R6/R7). BM=64, BN=256,
// BK=32, 4 waves. 1D grid of 768 blocks, longest-job-first. Double-buffered
// LDS + 1-deep prefetch, single barrier per K-step.
__global__ __launch_bounds__(256, 3) void gemm_ln(
    const float* fv, const float* fs, const float* fc,
    const u16* wWv, const u16* wWs, const u16* wWc,
    const float* bv, const float* gv, const float* bev,
    const float* bs, const float* gs, const float* bes,
    const float* bc, const float* gc_, const float* bec,
    u16* stack) {
    __shared__ alignas(16) char smem[45568];
    u16* sC = (u16*)smem;
    float* redS = (float*)(smem + 43008);   // [64][4]
    float* redQ = (float*)(smem + 44032);   // [64][4]
    float* mvS  = (float*)(smem + 45056);   // [64][2] mean,rstd

    int bid = blockIdx.x;
    int slot, mblk;
    if (bid < 256)      { slot = 0; mblk = bid; }
    else if (bid < 512) { slot = 1; mblk = bid - 256; }
    else                { slot = 2; mblk = bid - 512; }

    const float* A; const u16* W; const float* bias; const float* gg; const float* be; int K;
    if (slot == 0)      { A = fv; W = wWv; bias = bv; gg = gv;  be = bev; K = 2048; }
    else if (slot == 1) { A = fs; W = wWs; bias = bs; gg = gs;  be = bes; K = 1024; }
    else                { A = fc; W = wWc; bias = bc; gg = gc_; be = bec; K = 512;  }

    int t = threadIdx.x, wv = t >> 6, ln = t & 63, q = ln >> 4, l15 = ln & 15;
    int m0 = mblk * 64;

    fx4 zero = {0.f, 0.f, 0.f, 0.f};
    fx4 acc[4][4];
    #pragma unroll
    for (int mi = 0; mi < 4; ++mi)
        #pragma unroll
        for (int ni = 0; ni < 4; ++ni) acc[mi][ni] = zero;

    int rowA = t >> 2, ca = t & 3;                       // 64 rows x 4 chunks-of-8
    const float* aBase = A + (size_t)(m0 + rowA) * K + ca * 8;
    int sAwOff = rowA * 40 + ca * 8;                     // elem offset within sA buf

    int bN[4], bKc[4], bDst[4];
    #pragma unroll
    for (int i = 0; i < 4; ++i) {
        int d = wv * 256 + i * 64 + ln;
        bN[i] = d >> 2;
        bKc[i] = (d & 3) ^ ((bN[i] >> 1) & 3);
        bDst[i] = (wv * 256 + i * 64) * 16;              // byte offset in sB buf
    }

    int niter = K >> 5;

    // ---- prologue: stage tile 0 into buf 0
    {
        float4 f0 = *(const float4*)(aBase);
        float4 f1 = *(const float4*)(aBase + 4);
        #pragma unroll
        for (int i = 0; i < 4; ++i)
            gld16(smem + 10240 + bDst[i], W + (size_t)bN[i] * K + bKc[i] * 8);
        union { u16 us[8]; uint4 v; } pk;
        pk.us[0] = f2bf(f0.x); pk.us[1] = f2bf(f0.y); pk.us[2] = f2bf(f0.z); pk.us[3] = f2bf(f0.w);
        pk.us[4] = f2bf(f1.x); pk.us[5] = f2bf(f1.y); pk.us[6] = f2bf(f1.z); pk.us[7] = f2bf(f1.w);
        *(uint4*)((u16*)smem + sAwOff) = pk.v;
    }
    __syncthreads();

    for (int kt = 0; kt < niter; ++kt) {
        int cur = kt & 1, nxt_b = (kt + 1) & 1;
        u16* sAc = (u16*)(smem + cur * 5120);
        u16* sBc = (u16*)(smem + 10240 + cur * 16384);
        int has_next = (kt + 1) < niter;

        float4 nf0, nf1;
        if (has_next) {
            nf0 = *(const float4*)(aBase + (kt + 1) * 32);
            nf1 = *(const float4*)(aBase + (kt + 1) * 32 + 4);
            char* sBn = smem + 10240 + nxt_b * 16384;
            #pragma unroll
            for (int i = 0; i < 4; ++i)
                gld16(sBn + bDst[i], W + (size_t)bN[i] * K + (kt + 1) * 32 + bKc[i] * 8);
        }

        bf16x8 af[4], bfr[4];
        #pragma unroll
        for (int mi = 0; mi < 4; ++mi)
            af[mi] = *(const bf16x8*)(sAc + (mi * 16 + l15) * 40 + q * 8);
        #pragma unroll
        for (int ni = 0; ni < 4; ++ni) {
            int n = wv * 64 + ni * 16 + l15;
            int ch = n * 4 + (q ^ ((n >> 1) & 3));
            bfr[ni] = *(const bf16x8*)(sBc + ch * 8);
        }
        #pragma unroll
        for (int mi = 0; mi < 4; ++mi)
            #pragma unroll
            for (int ni = 0; ni < 4; ++ni)
                acc[mi][ni] = MFMA_BF16(af[mi], bfr[ni], acc[mi][ni]);

        if (has_next) {
            union { u16 us[8]; uint4 v; } pk;
            pk.us[0] = f2bf(nf0.x); pk.us[1] = f2bf(nf0.y); pk.us[2] = f2bf(nf0.z); pk.us[3] = f2bf(nf0.w);
            pk.us[4] = f2bf(nf1.x); pk.us[5] = f2bf(nf1.y); pk.us[6] = f2bf(nf1.z); pk.us[7] = f2bf(nf1.w);
            *(uint4*)((u16*)(smem + nxt_b * 5120) + sAwOff) = pk.v;
        }
        __syncthreads();
    }

    // epilogue: bias, LN stats from registers, normalize, write bf16
    float biasv[4], gvv[4], bevv[4];
    #pragma unroll
    for (int ni = 0; ni < 4; ++ni) {
        int col = wv * 64 + ni * 16 + l15;
        biasv[ni] = bias[col]; gvv[ni] = gg[col]; bevv[ni] = be[col];
    }
    #pragma unroll
    for (int mi = 0; mi < 4; ++mi)
        #pragma unroll
        for (int ni = 0; ni < 4; ++ni)
            #pragma unroll
            for (int r = 0; r < 4; ++r) acc[mi][ni][r] += biasv[ni];
    #pragma unroll
    for (int mi = 0; mi < 4; ++mi) {
        #pragma unroll
        for (int r = 0; r < 4; ++r) {
            float s = 0.f, qq = 0.f;
            #pragma unroll
            for (int ni = 0; ni < 4; ++ni) { float x = acc[mi][ni][r]; s += x; qq += x * x; }
            #pragma unroll
            for (int m = 1; m < 16; m <<= 1) { s += __shfl_xor(s, m, 64); qq += __shfl_xor(qq, m, 64); }
            if (l15 == 0) { int rho = mi * 16 + q * 4 + r; redS[rho * 4 + wv] = s; redQ[rho * 4 + wv] = qq; }
        }
    }
    __syncthreads();
    if (t < 64) {
        float s = redS[t * 4] + redS[t * 4 + 1] + redS[t * 4 + 2] + redS[t * 4 + 3];
        float qq = redQ[t * 4] + redQ[t * 4 + 1] + redQ[t * 4 + 2] + redQ[t * 4 + 3];
        float mean = s * (1.f / 256.f);
        float var = qq * (1.f / 256.f) - mean * mean;
        mvS[t * 2] = mean; mvS[t * 2 + 1] = rsqrtf(var + 1e-5f);
    }
    __syncthreads();
    #pragma unroll
    for (int mi = 0; mi < 4; ++mi) {
        #pragma unroll
        for (int r = 0; r < 4; ++r) {
            int rho = mi * 16 + q * 4 + r;
            float mean = mvS[rho * 2], rstd = mvS[rho * 2 + 1];
            #pragma unroll
            for (int ni = 0; ni < 4; ++ni) {
                int col = wv * 64 + ni * 16 + l15;
                float x = (acc[mi][ni][r] - mean) * rstd * gvv[ni] + bevv[ni];
                sC[rho * 256 + col] = f2bf(x);
            }
        }
    }
    __syncthreads();
    u16* outp = stack + (size_t)m0 * 768 + slot * 256;
    #pragma unroll
    for (int it = 0; it < 8; ++it) {
        int idx = t + it * 256;
        int row = idx >> 5, c = idx & 31;
        uint4 v = *(const uint4*)(sC + row * 256 + c * 8);
        *(uint4*)(outp + (size_t)row * 768 + c * 8) = v;
    }
}

// ------------------------------------------------------ K2: qkv = stack@in_w.T
// R3 variant verbatim. M=49152, K=256, N=768. BM=128, BN=128, 4 waves in 2x2.
// 3-buffer depth-2 counted-vmcnt pipeline.
__global__ __launch_bounds__(256, 3) void gemm_qkv(const u16* stack, const u16* W, const float* in_b,
                                                   u16* qkv) {
    __shared__ alignas(16) char smem[49152];
    u16* sC = (u16*)smem;            // epilogue [128][128] overlay

    int t = threadIdx.x, wv = t >> 6, ln = t & 63, q = ln >> 4, l15 = ln & 15;
    int n0 = blockIdx.x * 128, m0 = blockIdx.y * 128;
    int wr = wv >> 1, wc = wv & 1;

    fx4 zero = {0.f, 0.f, 0.f, 0.f};
    fx4 acc[4][4];
    #pragma unroll
    for (int mi = 0; mi < 4; ++mi)
        #pragma unroll
        for (int ni = 0; ni < 4; ++ni) acc[mi][ni] = zero;

    int sR[2], sKc[2];
    #pragma unroll
    for (int i = 0; i < 2; ++i) {
        int d = wv * 128 + i * 64 + ln;
        sR[i] = d >> 2;
        sKc[i] = (d & 3) ^ ((sR[i] >> 1) & 3);
    }

#define QK_ISSUE(ktile, bufoff)                                                         \
    {                                                                                   \
        char* bA_ = smem + (bufoff);                                                    \
        char* bB_ = bA_ + 8192;                                                         \
        _Pragma("unroll")                                                               \
        for (int i_ = 0; i_ < 2; ++i_) {                                                \
            gld16(bA_ + (wv * 128 + i_ * 64) * 16,                                      \
                  stack + (size_t)(m0 + sR[i_]) * 256 + (ktile) * 32 + sKc[i_] * 8);    \
            gld16(bB_ + (wv * 128 + i_ * 64) * 16,                                      \
                  W + (size_t)(n0 + sR[i_]) * 256 + (ktile) * 32 + sKc[i_] * 8);        \
        }                                                                               \
    }

    QK_ISSUE(0, 0);
    QK_ISSUE(1, 16384);
    int cb = 0;
    for (int kt = 0; kt < 8; ++kt) {
        if (kt < 7) { WAIT_VM(4); } else { WAIT_VM(0); }
        __builtin_amdgcn_sched_barrier(0);
        __builtin_amdgcn_s_barrier();
        __builtin_amdgcn_sched_barrier(0);
        int nb = cb + 2; if (nb >= 3) nb -= 3;
        if (kt + 2 < 8) QK_ISSUE(kt + 2, nb * 16384);

        const u16* sAc = (const u16*)(smem + cb * 16384);
        const u16* sBc = (const u16*)(smem + cb * 16384 + 8192);
        bf16x8 af[4], bfr[4];
        #pragma unroll
        for (int mi = 0; mi < 4; ++mi) {
            int r = wr * 64 + mi * 16 + l15;
            int ch = r * 4 + (q ^ ((r >> 1) & 3));
            af[mi] = *(const bf16x8*)(sAc + ch * 8);
        }
        #pragma unroll
        for (int ni = 0; ni < 4; ++ni) {
            int n = wc * 64 + ni * 16 + l15;
            int ch = n * 4 + (q ^ ((n >> 1) & 3));
            bfr[ni] = *(const bf16x8*)(sBc + ch * 8);
        }
        __builtin_amdgcn_s_setprio(1);
        #pragma unroll
        for (int mi = 0; mi < 4; ++mi)
            #pragma unroll
            for (int ni = 0; ni < 4; ++ni)
                acc[mi][ni] = MFMA_BF16(af[mi], bfr[ni], acc[mi][ni]);
        __builtin_amdgcn_s_setprio(0);
        cb += 1; if (cb >= 3) cb -= 3;
    }
#undef QK_ISSUE
    __syncthreads();   // all waves done reading bufs before sC overlay

    float biasv[4];
    #pragma unroll
    for (int ni = 0; ni < 4; ++ni) biasv[ni] = in_b[n0 + wc * 64 + ni * 16 + l15];
    #pragma unroll
    for (int mi = 0; mi < 4; ++mi)
        #pragma unroll
        for (int ni = 0; ni < 4; ++ni)
            #pragma unroll
            for (int r = 0; r < 4; ++r) {
                int rl = wr * 64 + mi * 16 + q * 4 + r;
                int cl = wc * 64 + ni * 16 + l15;
                sC[rl * 128 + cl] = f2bf(acc[mi][ni][r] + biasv[ni]);
            }
    __syncthreads();
    #pragma unroll
    for (int it = 0; it < 8; ++it) {
        int idx = t + it * 256;
        int row = idx >> 4, c = idx & 15;
        uint4 v = *(const uint4*)(sC + row * 128 + c * 8);
        *(uint4*)(qkv + (size_t)(m0 + row) * 768 + n0 + c * 8) = v;
    }
}

// ---- K4: FUSED attention + out-proj + residual + LN + gating MLP + outputs
// BM=48 rows = 16 b's per block, grid 1024. Prologue (absorbed K3): stage this
// block's qkv rows (48x768) -- q|k half (49152B) then v (24576B, overlaying
// dead q|k rows 0..23) -- compute 16-b attention in LDS, write ctx directly
// into the XOR-swizzled r1 layout the GEMM loop reads. Then R3's out-proj
// GEMM + LN + gating, unchanged. Saves the K3 launch + 50MB ctx round-trip.
// LDS overlays: [0,49152) qk -> v(0..24576)+r1(24576..49152);
// [49152,65536) sS(attn) -> sB(GEMM) -> red/mv/h1/lg/gate (epilogue).
__global__ __launch_bounds__(256) void outproj_k(
    const u16* qkv, const u16* W, const float* out_b, const u16* stack,
    const float* gn, const float* gb, const u16* g1w, const float* g1b,
    const float* g2w, const float* g2b, float* outF, float* outG) {
    __shared__ alignas(16) char smem[65536];
    u16* qk  = (u16*)smem;                        // [48][512] q|k (attn phase)
    u16* vb  = (u16*)smem;                        // [48][256] v (overlays qk rows 0..23)
    u16* r1  = (u16*)(smem + 24576);              // 24576B swizzled ctx / stack / attended
    u16* sB  = (u16*)(smem + 49152);              // 16384B (GEMM k-loop)
    float* sS   = (float*)(smem + 49152);         // 576 scores (attn phase, pre-sB)
    float* redS = (float*)(smem + 49152);         // [48][4] (post-GEMM, overlays sB)
    float* redQ = (float*)(smem + 49920);
    float* mvS  = (float*)(smem + 50688);         // [48][2]
    float* h1S  = (float*)(smem + 51072);         // [16][64]
    float* lgS  = (float*)(smem + 55168);         // 48 logits
    float* gateS= (float*)(smem + 55360);         // 48 gates

    int t = threadIdx.x, wv = t >> 6, ln = t & 63, q = ln >> 4, l15 = ln & 15;
    int gr0 = blockIdx.x * 48, b0 = blockIdx.x * 16;

    // ---- attention prologue (was K3) ----
    // stage q|k halves: 3072 chunks of 16B (cols 0..511 of each of 48 rows)
    #pragma unroll
    for (int i = 0; i < 12; ++i) {
        int d = i * 256 + t;
        int row = d >> 6, cc = d & 63;
        gld16((char*)smem + d * 16, qkv + (size_t)(gr0 + row) * 768 + cc * 8);
    }
    __syncthreads();
    // scores: 576 items = 16b*4h*9(i,j)
    #pragma unroll
    for (int it = 0; it < 3; ++it) {
        int idx = t + it * 256;
        if (idx < 576) {
            int b = idx / 36, rem = idx % 36, h = rem / 9, pp = rem % 9, i = pp / 3, j = pp % 3;
            const u16* qp = qk + (b * 3 + i) * 512 + h * 64;
            const u16* kp = qk + (b * 3 + j) * 512 + 256 + h * 64;
            float acc = 0.f;
            #pragma unroll
            for (int c = 0; c < 8; ++c) {
                uint4 qa = *(const uint4*)(qp + c * 8);
                uint4 ka = *(const uint4*)(kp + c * 8);
                acc += bfpair_dot(qa.x, ka.x) + bfpair_dot(qa.y, ka.y) +
                       bfpair_dot(qa.z, ka.z) + bfpair_dot(qa.w, ka.w);
            }
            sS[idx] = acc * 0.125f;  // /sqrt(64)
        }
    }
    __syncthreads();
    // stage v (1536 chunks, overwrites qk rows 0..23 -- scores already done)
    #pragma unroll
    for (int i = 0; i < 6; ++i) {
        int d = i * 256 + t;
        int row = d >> 5, cc = d & 31;
        gld16((char*)smem + d * 16, qkv + (size_t)(gr0 + row) * 768 + 512 + cc * 8);
    }
    if (t < 192) {  // softmax over j, t = b*12 + h*3 + i
        int b3 = t * 3;
        float s0 = sS[b3], s1 = sS[b3 + 1], s2 = sS[b3 + 2];
        float m = fmaxf(s0, fmaxf(s1, s2));
        float e0 = __expf(s0 - m), e1 = __expf(s1 - m), e2 = __expf(s2 - m);
        float inv = 1.f / (e0 + e1 + e2);
        sS[b3] = e0 * inv; sS[b3 + 1] = e1 * inv; sS[b3 + 2] = e2 * inv;
    }
    __syncthreads();   // drains v DMA + softmax
    // ctx -> r1 (swizzled): 1536 items = 16b * 3i * 32 chunks-of-8
    #pragma unroll
    for (int it = 0; it < 6; ++it) {
        int idx = t + it * 256;
        int b = idx / 96, rem = idx % 96, i = rem / 32, c = rem & 31, h = c >> 3;
        int pbase = b * 36 + h * 9 + i * 3;
        float o[8];
        #pragma unroll
        for (int e = 0; e < 8; ++e) o[e] = 0.f;
        #pragma unroll
        for (int j = 0; j < 3; ++j) {
            float p = sS[pbase + j];
            uint4 va = *(const uint4*)(vb + (b * 3 + j) * 256 + c * 8);
            unsigned uu[4] = {va.x, va.y, va.z, va.w};
            #pragma unroll
            for (int pr = 0; pr < 4; ++pr) {
                union { unsigned u; float f; } lo, hi;
                lo.u = uu[pr] << 16; hi.u = uu[pr] & 0xffff0000u;
                o[2 * pr]     += p * lo.f;
                o[2 * pr + 1] += p * hi.f;
            }
        }
        union { u16 us[8]; uint4 v; } pk;
        #pragma unroll
        for (int e = 0; e < 8; ++e) pk.us[e] = f2bf(o[e]);
        int row = b * 3 + i;
        *(uint4*)(r1 + (row * 32 + (c ^ (row & 7))) * 8) = pk.v;
    }
    __syncthreads();

    // ---- out-proj GEMM (R3 structure, r1 already holds swizzled ctx) ----
    fx4 zero = {0.f, 0.f, 0.f, 0.f};
    fx4 acc[3][4];
    #pragma unroll
    for (int mi = 0; mi < 3; ++mi)
        #pragma unroll
        for (int ni = 0; ni < 4; ++ni) acc[mi][ni] = zero;

    for (int kt = 0; kt < 8; ++kt) {
        #pragma unroll
        for (int i = 0; i < 4; ++i) {
            int d = wv * 256 + i * 64 + ln;
            int n = d >> 2, p = d & 3;
            int kc = p ^ ((n >> 1) & 3);
            gld16((char*)sB + (wv * 256 + i * 64) * 16, W + (size_t)n * 256 + kt * 32 + kc * 8);
        }
        __syncthreads();
        bf16x8 af[3], bfr[4];
        #pragma unroll
        for (int mi = 0; mi < 3; ++mi) {
            int row = mi * 16 + l15;
            int ch = row * 32 + ((kt * 4 + q) ^ (row & 7));
            af[mi] = *(const bf16x8*)(r1 + ch * 8);
        }
        #pragma unroll
        for (int ni = 0; ni < 4; ++ni) {
            int n = wv * 64 + ni * 16 + l15;
            int ch = n * 4 + (q ^ ((n >> 1) & 3));
            bfr[ni] = *(const bf16x8*)(sB + ch * 8);
        }
        #pragma unroll
        for (int mi = 0; mi < 3; ++mi)
            #pragma unroll
            for (int ni = 0; ni < 4; ++ni)
                acc[mi][ni] = MFMA_BF16(af[mi], bfr[ni], acc[mi][ni]);
        __syncthreads();
    }

    // stage stack tile [48][256] (contiguous in global) into r1
    #pragma unroll
    for (int i = 0; i < 6; ++i) {
        int d = wv * 384 + i * 64 + ln;
        gld16((char*)r1 + (wv * 384 + i * 64) * 16, stack + (size_t)gr0 * 256 + (size_t)d * 8);
    }
    __syncthreads();

    float obv[4], gnv[4], gbv[4];
    #pragma unroll
    for (int ni = 0; ni < 4; ++ni) {
        int col = wv * 64 + ni * 16 + l15;
        obv[ni] = out_b[col]; gnv[ni] = gn[col]; gbv[ni] = gb[col];
    }
    #pragma unroll
    for (int mi = 0; mi < 3; ++mi)
        #pragma unroll
        for (int ni = 0; ni < 4; ++ni)
            #pragma unroll
            for (int r = 0; r < 4; ++r) {
                int rho = mi * 16 + q * 4 + r;
                int col = wv * 64 + ni * 16 + l15;
                acc[mi][ni][r] += obv[ni] + bf2f(r1[rho * 256 + col]);
            }
    // LN stats
    #pragma unroll
    for (int mi = 0; mi < 3; ++mi) {
        #pragma unroll
        for (int r = 0; r < 4; ++r) {
            float s = 0.f, qq = 0.f;
            #pragma unroll
            for (int ni = 0; ni < 4; ++ni) { float x = acc[mi][ni][r]; s += x; qq += x * x; }
            #pragma unroll
            for (int m = 1; m < 16; m <<= 1) { s += __shfl_xor(s, m, 64); qq += __shfl_xor(qq, m, 64); }
            if (l15 == 0) { int rho = mi * 16 + q * 4 + r; redS[rho * 4 + wv] = s; redQ[rho * 4 + wv] = qq; }
        }
    }
    __syncthreads();
    if (t < 48) {
        float s = redS[t * 4] + redS[t * 4 + 1] + redS[t * 4 + 2] + redS[t * 4 + 3];
        float qq = redQ[t * 4] + redQ[t * 4 + 1] + redQ[t * 4 + 2] + redQ[t * 4 + 3];
        float mean = s * (1.f / 256.f);
        float var = qq * (1.f / 256.f) - mean * mean;
        mvS[t * 2] = mean; mvS[t * 2 + 1] = rsqrtf(var + 1e-5f);
    }
    __syncthreads();
    // normalize -> rowBuf (r1, swizzled as [16 b][96 chunks], chunk = bl*96 + (kidx^(bl&7)))
    #pragma unroll
    for (int mi = 0; mi < 3; ++mi) {
        #pragma unroll
        for (int r = 0; r < 4; ++r) {
            int rho = mi * 16 + q * 4 + r;
            float mean = mvS[rho * 2], rstd = mvS[rho * 2 + 1];
            int bl = rho / 3, sl = rho - bl * 3;
            #pragma unroll
            for (int ni = 0; ni < 4; ++ni) {
                int col = wv * 64 + ni * 16 + l15;
                float x = (acc[mi][ni][r] - mean) * rstd * gnv[ni] + gbv[ni];
                int k = sl * 256 + col;
                int kidx = k >> 3, wn = k & 7;
                r1[(bl * 96 + (kidx ^ (bl & 7))) * 8 + wn] = f2bf(x);
            }
        }
    }
    __syncthreads();
    // gating MFMA: h1[16 b][64] = attended_flat(16x768) @ g1w.T ; wave wv owns cols wv*16..+15
    fx4 ag = zero;
    for (int kt = 0; kt < 24; ++kt) {
        int bl = l15;
        int kidx = kt * 4 + q;
        bf16x8 afr = *(const bf16x8*)(r1 + (bl * 96 + (kidx ^ (bl & 7))) * 8);
        int n = wv * 16 + l15;
        bf16x8 bfr2 = *(const bf16x8*)(g1w + (size_t)n * 768 + kt * 32 + q * 8);
        ag = MFMA_BF16(afr, bfr2, ag);
    }
    #pragma unroll
    for (int r = 0; r < 4; ++r) {
        int bl = q * 4 + r, n = wv * 16 + l15;
        float x = ag[r] + g1b[n];
        h1S[bl * 64 + n] = 0.5f * x * (1.f + erff(x * 0.70710678118f));
    }
    __syncthreads();
    if (t < 48) {  // logits: t = bl*3 + s
        int bl = t / 3, s = t - bl * 3;
        float a = g2b[s];
        #pragma unroll
        for (int k = 0; k < 64; ++k) a += h1S[bl * 64 + k] * g2w[s * 64 + k];
        lgS[t] = a;
    }
    __syncthreads();
    if (t < 48) {
        int bl = t / 3, s = t - bl * 3;
        float l0 = lgS[bl * 3], l1 = lgS[bl * 3 + 1], l2 = lgS[bl * 3 + 2];
        float m = fmaxf(l0, fmaxf(l1, l2));
        float e0 = __expf(l0 - m), e1 = __expf(l1 - m), e2 = __expf(l2 - m);
        float inv = 1.f / (e0 + e1 + e2);
        float gsel = ((s == 0) ? e0 : (s == 1) ? e1 : e2) * inv;
        gateS[t] = gsel;
        outG[(size_t)(b0 + bl) * 3 + s] = gsel;
    }
    __syncthreads();
    // fused = sum_s gate[s] * attended[s]
    #pragma unroll
    for (int it = 0; it < 2; ++it) {
        int idx = t + it * 256;
        int b = idx >> 5, c = idx & 31;
        float g0 = gateS[b * 3], g1 = gateS[b * 3 + 1], g2 = gateS[b * 3 + 2];
        float o[8];
        #pragma unroll
        for (int e = 0; e < 8; ++e) o[e] = 0.f;
        #pragma unroll
        for (int s = 0; s < 3; ++s) {
            float gw = (s == 0) ? g0 : (s == 1) ? g1 : g2;
            int kidx = s * 32 + c;
            uint4 raw = *(const uint4*)(r1 + (b * 96 + (kidx ^ (b & 7))) * 8);
            unsigned uu[4] = {raw.x, raw.y, raw.z, raw.w};
            #pragma unroll
            for (int pr = 0; pr < 4; ++pr) {
                union { unsigned u; float f; } lo, hi;
                lo.u = uu[pr] << 16; hi.u = uu[pr] & 0xffff0000u;
                o[2 * pr]     += gw * lo.f;
                o[2 * pr + 1] += gw * hi.f;
            }
        }
        float* op = outF + (size_t)(b0 + b) * 256 + c * 8;
        float4 v0; v0.x = o[0]; v0.y = o[1]; v0.z = o[2]; v0.w = o[3];
        float4 v1; v1.x = o[4]; v1.y = o[5]; v1.z = o[6]; v1.w = o[7];
        *(float4*)op = v0;
        *(float4*)(op + 4) = v1;
    }
}

extern "C" void kernel_launch(void* const* d_in, const int* in_sizes, int n_in,
                              void* d_out, int out_size, void* d_ws, size_t ws_size,
                              hipStream_t stream) {
    (void)in_sizes; (void)n_in; (void)out_size; (void)ws_size;
    const float* fv   = (const float*)d_in[0];
    const float* fs   = (const float*)d_in[1];
    const float* fc   = (const float*)d_in[2];
    const float* Wv   = (const float*)d_in[3];
    const float* bv   = (const float*)d_in[4];
    const float* gv   = (const float*)d_in[5];
    const float* bev  = (const float*)d_in[6];
    const float* Ws   = (const float*)d_in[7];
    const float* bs   = (const float*)d_in[8];
    const float* gs   = (const float*)d_in[9];
    const float* bes  = (const float*)d_in[10];
    const float* Wc   = (const float*)d_in[11];
    const float* bc   = (const float*)d_in[12];
    const float* gc_  = (const float*)d_in[13];
    const float* bec  = (const float*)d_in[14];
    const float* in_w = (const float*)d_in[15];
    const float* in_b = (const float*)d_in[16];
    const float* out_w= (const float*)d_in[17];
    const float* out_b= (const float*)d_in[18];
    const float* gn   = (const float*)d_in[19];
    const float* gb   = (const float*)d_in[20];
    const float* g1w  = (const float*)d_in[21];
    const float* g1b  = (const float*)d_in[22];
    const float* g2w  = (const float*)d_in[23];
    const float* g2b  = (const float*)d_in[24];

    u16* w0    = (u16*)d_ws;
    u16* wWv   = w0;               // 524288
    u16* wWs   = w0 + 524288;      // 262144
    u16* wWc   = w0 + 786432;      // 131072
    u16* wIn   = w0 + 917504;      // 196608
    u16* wOut  = w0 + 1114112;     // 65536
    u16* wG1   = w0 + 1179648;     // 49152
    u16* stack = w0 + 1228800;     // 49152*256
    u16* qkv   = w0 + 13811712;    // 49152*768
    float* outF = (float*)d_out;
    float* outG = outF + (size_t)16384 * 256;

    cvt_w<<<4800, 256, 0, stream>>>(Wv, Ws, Wc, in_w, out_w, g1w, w0);
    gemm_ln<<<768, 256, 0, stream>>>(fv, fs, fc, wWv, wWs, wWc,
                                     bv, gv, bev, bs, gs, bes, bc, gc_, bec, stack);
    gemm_qkv<<<dim3(6, 384), 256, 0, stream>>>(stack, wIn, in_b, qkv);
    outproj_k<<<1024, 256, 0, stream>>>(qkv, wOut, out_b, stack, gn, gb,
                                        wG1, g1b, g2w, g2b, outF, outG);
}